// Round 19
// baseline (125.705 us; speedup 1.0000x reference)
//
#include <hip/hip_runtime.h>
#include <hip/hip_bf16.h>

#define NN 8192
#define IN_F 256
#define OF 128

typedef float  f32x4   __attribute__((ext_vector_type(4)));
typedef float  f32x16  __attribute__((ext_vector_type(16)));
typedef short  short8v __attribute__((ext_vector_type(8)));
typedef int    int4v   __attribute__((ext_vector_type(4)));
typedef __bf16 bf16x8v __attribute__((ext_vector_type(8)));

__device__ __forceinline__ unsigned short bf16_bits(float x) {
    __bf16 b = (__bf16)x;
    return __builtin_bit_cast(unsigned short, b);
}

// 32x32x16 bf16 MFMA (gfx950): A row=lane&31, k=8*(lane>>5)+e;
// B col=lane&31, k=8*(lane>>5)+e; D col=lane&31, row=(q&3)+8*(q>>2)+4*(lane>>5)
// (C/D m74/m101-verified; A/B by the verified 16x16x32 pattern analogy).
__device__ __forceinline__ f32x16 mfma3216(short8v a, short8v b, f32x16 c) {
#if __has_builtin(__builtin_amdgcn_mfma_f32_32x32x16_bf16)
    return __builtin_amdgcn_mfma_f32_32x32x16_bf16(
        __builtin_bit_cast(bf16x8v, a), __builtin_bit_cast(bf16x8v, b), c, 0, 0, 0);
#else
    asm("v_mfma_f32_32x32x16_bf16 %0, %1, %2, %0" : "+v"(c) : "v"(a), "v"(b));
    return c;
#endif
}

// async global->LDS, 16B per lane; LDS dest = wave-uniform base + lane*16
__device__ __forceinline__ void gload_lds16(const void* gsrc, void* lds) {
    __builtin_amdgcn_global_load_lds(
        (const __attribute__((address_space(1))) int*)gsrc,
        (__attribute__((address_space(3))) int*)lds, 16, 0, 0);
}

// ---------------------------------------------------------------------------
// Kernel A: h = X @ W (f32, LDS-staged W).  Emits HtB in 32x32x16 B-fragment
// order: for h[j][f]:  kt16=j>>4, g'=(j>>3)&1, e=j&7, ft=f>>5, fc=f&31
//   short index = ((kt16*4 + ft)*64 + fc + 32*g')*8 + e    (4 KB per kt16)
// Also f_src = h.a[:OF], f_dst = h.a[OF:].
// ---------------------------------------------------------------------------
__global__ __launch_bounds__(256) void gat_prep(
    const float* __restrict__ X, const float* __restrict__ W,
    const float* __restrict__ a, unsigned short* __restrict__ HtB,
    float* __restrict__ f_src, float* __restrict__ f_dst)
{
    __shared__ float Wlds[IN_F * OF];   // 128 KiB
    __shared__ float red_s[32][8];
    __shared__ float red_d[32][8];

    const int t = threadIdx.x;
    {
        const f32x4* Wv = (const f32x4*)W;
        f32x4*       Wl = (f32x4*)Wlds;
        #pragma unroll
        for (int c = 0; c < 32; ++c) Wl[c * 256 + t] = Wv[c * 256 + t];
    }
    __syncthreads();

    const int row = t & 31;
    const int sub = t >> 5;            // 16-feature block
    const int i   = blockIdx.x * 32 + row;

    f32x4 acc[4] = {};
    const float* xrow = X + (size_t)i * IN_F;

    #pragma unroll 4
    for (int kk = 0; kk < IN_F; kk += 4) {
        f32x4 xv = *(const f32x4*)(xrow + kk);
        #pragma unroll
        for (int e = 0; e < 4; ++e) {
            const f32x4* wr = (const f32x4*)(Wlds + (kk + e) * OF + sub * 16);
            float xs = xv[e];
            #pragma unroll
            for (int c4 = 0; c4 < 4; ++c4) acc[c4] += xs * wr[c4];
        }
    }

    const int kt16 = i >> 4;
    const int gq   = (i >> 3) & 1;
    const int eq   = i & 7;
    const int ft   = sub >> 1;

    float ps = 0.f, pd = 0.f;
    #pragma unroll
    for (int c4 = 0; c4 < 4; ++c4) {
        #pragma unroll
        for (int e = 0; e < 4; ++e) {
            float v = acc[c4][e];
            int   c = c4 * 4 + e;              // 0..15 within feature block
            ps += v * a[sub * 16 + c];
            pd += v * a[OF + sub * 16 + c];
            const int fc = (sub & 1) * 16 + c; // 0..31 within 32-feat tile
            HtB[(size_t)(((kt16 * 4 + ft) * 64) + fc + 32 * gq) * 8 + eq]
                = bf16_bits(v);
        }
    }
    red_s[row][sub] = ps;
    red_d[row][sub] = pd;
    __syncthreads();
    if (t < 32) {
        float s = 0.f;
        #pragma unroll
        for (int s8 = 0; s8 < 8; ++s8) s += red_s[t][s8];
        f_src[blockIdx.x * 32 + t] = s;
    } else if (t < 64) {
        const int r2 = t - 32;
        float s = 0.f;
        #pragma unroll
        for (int s8 = 0; s8 < 8; ++s8) s += red_d[r2][s8];
        f_dst[blockIdx.x * 32 + r2] = s;
    }
}

// ---------------------------------------------------------------------------
// gat_row4 (v19): R18 structure with 32x32x16 MFMA (half the MFMA instrs).
// Grid = 32 row-blocks x 8 k-splits = 256 blocks (1/CU) x 512 threads.
// Wave w owns 32 rows: rowbase + w*32 + (lane&31) -- 1:1 with the A-fragment.
// K-range = ks*1024..+1023 = 64 kt16; 4 supersteps x 16 kt16 (64 KB slab,
// double-buffered via global_load_lds; +4 KB f_dst slice = 132 KiB LDS).
// Per kt16/wave: 2 adj int4 (32B/lane contiguous) + 2 f_dst LDS reads +
// 4 ds_read_b128 + 8 exp + 4 MFMA(32x32x16).  adj depth-1 register pipeline.
// ---------------------------------------------------------------------------
__global__ __launch_bounds__(512, 2) void gat_row4(
    const int* __restrict__ adj, const char* __restrict__ htb,
    const float* __restrict__ f_src, const float* __restrict__ f_dst,
    float* __restrict__ part, float* __restrict__ rsPart)
{
    __shared__ __align__(16) char smem[135168];
    // [0,131072): 2 x 64KiB B dbuf (epilogue: lt per wave)
    // [131072, 135168): f_dst slice (1024 f32)

    const int tid  = threadIdx.x;
    const int w    = tid >> 6;
    const int lane = tid & 63;
    const int rl   = lane & 31;        // row within wave tile
    const int gp   = lane >> 5;        // k-half
    const int ms   = blockIdx.x >> 3;
    const int ks   = blockIdx.x & 7;
    const int rowbase = ms * 256;
    const int row  = rowbase + w * 32 + rl;

    const float fsrc_r = f_src[row];
    const int*  aptr = adj + (size_t)row * NN + ks * 1024 + gp * 8;
    const char* gB   = htb + (size_t)ks * 262144;   // 64 kt16 x 4 KB

    float* fdl = (float*)(smem + 131072);
    if (tid < 256)
        *((f32x4*)fdl + tid) = *((const f32x4*)(f_dst + ks * 1024) + tid);

    f32x16 acc[4] = {};
    float psum = 0.f;

    // prologue: stage superstep 0 into buf 0 (64 KB, linear; 8 x 16B/thread)
    #pragma unroll
    for (int u = 0; u < 8; ++u)
        gload_lds16(gB + (size_t)(u * 512 + tid) * 16,
                    smem + (size_t)(u * 512 + tid) * 16);

    // adj depth-1 pipeline: current regs for kt16 index 0
    int4v ca0 = *(const int4v*)(aptr);
    int4v ca1 = *(const int4v*)(aptr + 4);

    int buf = 0;
    for (int ss = 0; ss < 4; ++ss) {
        __syncthreads();   // stage(ss) resident (vmcnt drain); buf^1 free

        if (ss + 1 < 4) {
            const char* gs = gB + (size_t)(ss + 1) * 65536;
            #pragma unroll
            for (int u = 0; u < 8; ++u)
                gload_lds16(gs + (size_t)(u * 512 + tid) * 16,
                            smem + (buf ^ 1) * 65536 + (size_t)(u * 512 + tid) * 16);
        }

        #pragma unroll
        for (int ktl = 0; ktl < 16; ++ktl) {
            const int i  = ss * 16 + ktl;        // kt16 local index 0..63
            const int in = (i + 1 < 64) ? i + 1 : i;

            // issue NEXT kt16's adj (renamed regs, stays in flight)
            const int4v na0 = *(const int4v*)(aptr + in * 16);
            const int4v na1 = *(const int4v*)(aptr + in * 16 + 4);

            // f_dst from LDS
            const f32x4 fd0 = *(const f32x4*)(fdl + i * 16 + gp * 8);
            const f32x4 fd1 = *(const f32x4*)(fdl + i * 16 + gp * 8 + 4);

            // B fragments: 4 x ds_read_b128 from the staged slab
            const char* lb = smem + buf * 65536 + ktl * 4096 + (size_t)lane * 16;
            short8v bv[4];
            #pragma unroll
            for (int ft = 0; ft < 4; ++ft)
                bv[ft] = *(const short8v*)(lb + ft * 1024);

            __builtin_amdgcn_sched_barrier(0);   // pin loads above compute

            float p[8];
            #pragma unroll
            for (int e = 0; e < 4; ++e) {
                float s;
                s = fsrc_r + fd0[e]; s = s > 0.f ? s : 0.2f * s;
                p[e]     = (ca0[e] != 0) ? __expf(s) : 0.f;
                s = fsrc_r + fd1[e]; s = s > 0.f ? s : 0.2f * s;
                p[4 + e] = (ca1[e] != 0) ? __expf(s) : 0.f;
            }
            psum += ((p[0] + p[1]) + (p[2] + p[3]))
                  + ((p[4] + p[5]) + (p[6] + p[7]));
            const short8v af = { (short)bf16_bits(p[0]), (short)bf16_bits(p[1]),
                                 (short)bf16_bits(p[2]), (short)bf16_bits(p[3]),
                                 (short)bf16_bits(p[4]), (short)bf16_bits(p[5]),
                                 (short)bf16_bits(p[6]), (short)bf16_bits(p[7]) };

            #pragma unroll
            for (int ft = 0; ft < 4; ++ft)
                acc[ft] = mfma3216(af, bv[ft], acc[ft]);

            ca0 = na0; ca1 = na1;
        }
        buf ^= 1;
    }

    // rowsum partials: lane l and l+32 hold the two k-halves of row (lane&31)
    psum += __shfl_xor(psum, 32, 64);
    if (lane < 32)
        rsPart[(size_t)ks * NN + rowbase + w * 32 + lane] = psum;

    __syncthreads();   // all waves done reading stage buffers

    // wave-private LDS transpose (frag -> row-major 32x128), then coalesced
    float* lt = (float*)(smem + w * 16384);   // 16 KiB per wave
    #pragma unroll
    for (int ft = 0; ft < 4; ++ft)
        #pragma unroll
        for (int q = 0; q < 16; ++q) {
            const int rloc = (q & 3) + 8 * (q >> 2) + 4 * gp;
            lt[rloc * OF + ft * 32 + rl] = acc[ft][q];
        }

    float* pb = part + ((size_t)ks * NN + rowbase + w * 32) * OF;
    #pragma unroll
    for (int j = 0; j < 16; ++j) {
        const int idx = j * 64 + lane;       // f32x4 index in 32x128 tile
        *(f32x4*)(pb + (size_t)idx * 4) = *(const f32x4*)&lt[idx * 4];
    }
}

// ---------------------------------------------------------------------------
// Finish: out = relu( (sum_ks part[ks]) / (sum_ks rs[ks]) ).
// ---------------------------------------------------------------------------
__global__ __launch_bounds__(512) void gat_finish(
    const float* __restrict__ part, const float* __restrict__ rsPart,
    float* __restrict__ out)
{
    const int tg  = blockIdx.x * 512 + threadIdx.x;   // f32x4 index
    const int row = tg >> 5;

    f32x4 v = {};
    float den = 0.f;
    #pragma unroll
    for (int ks = 0; ks < 8; ++ks) {
        v   += *(const f32x4*)(part + (size_t)ks * NN * OF + (size_t)tg * 4);
        den += rsPart[(size_t)ks * NN + row];
    }
    const float inv = 1.0f / den;
    f32x4 o = v * inv;
    #pragma unroll
    for (int e = 0; e < 4; ++e) o[e] = fmaxf(o[e], 0.f);
    *(f32x4*)(out + (size_t)tg * 4) = o;
}

extern "C" void kernel_launch(void* const* d_in, const int* in_sizes, int n_in,
                              void* d_out, int out_size, void* d_ws, size_t ws_size,
                              hipStream_t stream) {
    const float* X   = (const float*)d_in[0];
    const int*   adj = (const int*)d_in[1];
    const float* W   = (const float*)d_in[2];
    const float* a   = (const float*)d_in[3];
    float* out = (float*)d_out;

    char* ws = (char*)d_ws;
    unsigned short* HtB    = (unsigned short*)ws;                  // 2 MiB
    float*          f_src  = (float*)(ws + 2097152);               // 32 KiB
    float*          f_dst  = (float*)(ws + 2097152 + 32768);       // 32 KiB
    float*          rsPart = (float*)(ws + 2162688);               // 256 KiB
    float*          part   = (float*)(ws + 2424832);               // 32 MiB

    gat_prep<<<NN / 32, 256, 0, stream>>>(X, W, a, HtB, f_src, f_dst);
    gat_row4<<<256, 512, 0, stream>>>(adj, (const char*)HtB,
                                      f_src, f_dst, part, rsPart);
    gat_finish<<<512, 512, 0, stream>>>(part, rsPart, out);
}